// Round 1
// baseline (482.372 us; speedup 1.0000x reference)
//
#include <hip/hip_runtime.h>
#include <hip/hip_bf16.h>

#define BATCH 2
#define SEQ   2048
#define NH    16
#define NKV   4
#define HD    128
#define KDIM  2048          // hidden size (GEMM K)
#define MROWS 4096          // BATCH*SEQ
#define NQKV  3072          // 2048 Q + 512 K + 512 V cols

typedef __attribute__((ext_vector_type(8))) short  s16x8;
typedef __attribute__((ext_vector_type(4))) short  s16x4;
typedef __attribute__((ext_vector_type(4))) float  f32x4;
typedef __attribute__((ext_vector_type(8))) __bf16 b16x8;

__device__ __forceinline__ unsigned short f2bf(float f) {
  union { float f; unsigned int u; } x; x.f = f;
  unsigned int r = (x.u + 0x7FFFu + ((x.u >> 16) & 1u)) >> 16;
  return (unsigned short)r;
}
__device__ __forceinline__ float bf2f(unsigned short h) {
  union { unsigned int u; float f; } x; x.u = ((unsigned int)h) << 16;
  return x.f;
}

__device__ __forceinline__ f32x4 MFMA16(s16x8 a, s16x8 b, f32x4 c) {
  return __builtin_amdgcn_mfma_f32_16x16x32_bf16(
      __builtin_bit_cast(b16x8, a), __builtin_bit_cast(b16x8, b), c, 0, 0, 0);
}

// ---------------- W (KxN f32) -> WT (NxK bf16) ----------------
__global__ __launch_bounds__(256) void transpose_convert(
    const float* __restrict__ W, unsigned short* __restrict__ WT, int Kd, int Nd) {
  __shared__ float tile[32][33];
  int n0 = blockIdx.x * 32, k0 = blockIdx.y * 32;
  int tx = threadIdx.x & 31, ty = threadIdx.x >> 5;  // ty 0..7
#pragma unroll
  for (int i = 0; i < 4; ++i)
    tile[ty + i * 8][tx] = W[(size_t)(k0 + ty + i * 8) * Nd + n0 + tx];
  __syncthreads();
#pragma unroll
  for (int i = 0; i < 4; ++i)
    WT[(size_t)(n0 + ty + i * 8) * Kd + k0 + tx] = f2bf(tile[tx][ty + i * 8]);
}

// ---------------- RoPE cos/sin table: [SEQ][64] x (cos,sin) f32 ----------------
__global__ __launch_bounds__(256) void rope_table_kernel(float* __restrict__ tbl) {
  int i = blockIdx.x * 256 + threadIdx.x;  // < SEQ*64
  int s = i >> 6, j = i & 63;
  float inv = powf(10000.0f, -(float)(2 * j) * (1.0f / 128.0f));
  float f = (float)s * inv;
  tbl[2 * i]     = cosf(f);
  tbl[2 * i + 1] = sinf(f);
}

// ---------------- QKV GEMM: A f32 (4096x2048) x BT bf16 (3072x2048) ----------------
__global__ __launch_bounds__(256) void gemm_qkv(
    const float* __restrict__ A, const unsigned short* __restrict__ BT,
    unsigned short* __restrict__ Qo, unsigned short* __restrict__ Ko,
    unsigned short* __restrict__ Vo) {
  __shared__ __align__(16) unsigned short la[128][32];
  __shared__ __align__(16) unsigned short lb[128][32];
  int tid = threadIdx.x, lane = tid & 63, w = tid >> 6;
  int m0 = blockIdx.y * 128, n0 = blockIdx.x * 128;
  int wr = (w >> 1) * 64, wc = (w & 1) * 64;
  int fr = lane & 15, kg = (lane >> 4) * 8, rg = (lane >> 4) * 4;
  f32x4 acc[4][4] = {};
  for (int kt = 0; kt < KDIM; kt += 32) {
    __syncthreads();
#pragma unroll
    for (int i = 0; i < 4; ++i) {  // A: 128x32 f32 -> bf16
      int idx = tid + i * 256;
      int row = idx >> 3, seg = idx & 7;
      float4 v = *(const float4*)(A + (size_t)(m0 + row) * KDIM + kt + seg * 4);
      s16x4 h;
      h[0] = (short)f2bf(v.x); h[1] = (short)f2bf(v.y);
      h[2] = (short)f2bf(v.z); h[3] = (short)f2bf(v.w);
      *(s16x4*)(&la[row][seg * 4]) = h;
    }
#pragma unroll
    for (int i = 0; i < 2; ++i) {  // B: 128x32 bf16
      int idx = tid + i * 256;
      int row = idx >> 2, seg = idx & 3;
      *(s16x8*)(&lb[row][seg * 8]) =
          *(const s16x8*)(BT + (size_t)(n0 + row) * KDIM + kt + seg * 8);
    }
    __syncthreads();
    s16x8 af[4], bf[4];
#pragma unroll
    for (int mi = 0; mi < 4; ++mi) af[mi] = *(const s16x8*)(&la[wr + mi * 16 + fr][kg]);
#pragma unroll
    for (int ni = 0; ni < 4; ++ni) bf[ni] = *(const s16x8*)(&lb[wc + ni * 16 + fr][kg]);
#pragma unroll
    for (int mi = 0; mi < 4; ++mi)
#pragma unroll
      for (int ni = 0; ni < 4; ++ni) acc[mi][ni] = MFMA16(af[mi], bf[ni], acc[mi][ni]);
  }
  int rbase = m0 + wr + rg;
#pragma unroll
  for (int ni = 0; ni < 4; ++ni) {
    int gn = n0 + wc + ni * 16 + fr;
    unsigned short* dst; int col, ldn;
    if (gn < 2048)      { dst = Qo; col = gn;        ldn = 2048; }
    else if (gn < 2560) { dst = Ko; col = gn - 2048; ldn = 512;  }
    else                { dst = Vo; col = gn - 2560; ldn = 512;  }
#pragma unroll
    for (int mi = 0; mi < 4; ++mi)
#pragma unroll
      for (int r = 0; r < 4; ++r)
        dst[(size_t)(rbase + mi * 16 + r) * ldn + col] = f2bf(acc[mi][ni][r]);
  }
}

// ---------------- O-proj GEMM: A bf16 (4096x2048) x WoT bf16 (2048x2048) -> f32 ----------------
__global__ __launch_bounds__(256) void gemm_out(
    const unsigned short* __restrict__ A, const unsigned short* __restrict__ BT,
    float* __restrict__ C) {
  __shared__ __align__(16) unsigned short la[128][32];
  __shared__ __align__(16) unsigned short lb[128][32];
  int tid = threadIdx.x, lane = tid & 63, w = tid >> 6;
  int m0 = blockIdx.y * 128, n0 = blockIdx.x * 128;
  int wr = (w >> 1) * 64, wc = (w & 1) * 64;
  int fr = lane & 15, kg = (lane >> 4) * 8, rg = (lane >> 4) * 4;
  f32x4 acc[4][4] = {};
  for (int kt = 0; kt < KDIM; kt += 32) {
    __syncthreads();
#pragma unroll
    for (int i = 0; i < 2; ++i) {
      int idx = tid + i * 256;
      int row = idx >> 2, seg = idx & 3;
      *(s16x8*)(&la[row][seg * 8]) =
          *(const s16x8*)(A + (size_t)(m0 + row) * KDIM + kt + seg * 8);
      *(s16x8*)(&lb[row][seg * 8]) =
          *(const s16x8*)(BT + (size_t)(n0 + row) * KDIM + kt + seg * 8);
    }
    __syncthreads();
    s16x8 af[4], bf[4];
#pragma unroll
    for (int mi = 0; mi < 4; ++mi) af[mi] = *(const s16x8*)(&la[wr + mi * 16 + fr][kg]);
#pragma unroll
    for (int ni = 0; ni < 4; ++ni) bf[ni] = *(const s16x8*)(&lb[wc + ni * 16 + fr][kg]);
#pragma unroll
    for (int mi = 0; mi < 4; ++mi)
#pragma unroll
      for (int ni = 0; ni < 4; ++ni) acc[mi][ni] = MFMA16(af[mi], bf[ni], acc[mi][ni]);
  }
  int rbase = m0 + wr + rg;
#pragma unroll
  for (int ni = 0; ni < 4; ++ni) {
    int gn = n0 + wc + ni * 16 + fr;
#pragma unroll
    for (int mi = 0; mi < 4; ++mi)
#pragma unroll
      for (int r = 0; r < 4; ++r)
        C[(size_t)(rbase + mi * 16 + r) * 2048 + gn] = acc[mi][ni][r];
  }
}

// ---------------- RoPE (in-place on bf16 X: [4096 rows][HEADS*128]) ----------------
__global__ __launch_bounds__(256) void rope_kernel(
    unsigned short* __restrict__ X, const float* __restrict__ tbl, int HEADS) {
  __shared__ __align__(16) unsigned short xs[32][128];
  int tid = threadIdx.x;
  int p0 = blockIdx.x * 32;  // 32 (row,head) pairs per block
#pragma unroll
  for (int i = 0; i < 2; ++i) {
    int idx = tid + i * 256;
    int pr = idx >> 4, seg = idx & 15;
    int pair = p0 + pr;
    int row = pair / HEADS, hh = pair % HEADS;
    *(s16x8*)(&xs[pr][seg * 8]) =
        *(const s16x8*)(X + ((size_t)row * HEADS + hh) * HD + seg * 8);
  }
  __syncthreads();
  int pr = tid >> 3, jb = (tid & 7) * 8;
  int pair = p0 + pr;
  int row = pair / HEADS, hh = pair % HEADS;
  int s = row & (SEQ - 1);
  s16x8 o0, o1;
#pragma unroll
  for (int j0 = 0; j0 < 8; ++j0) {
    int j = jb + j0;
    float c  = tbl[(s * 64 + j) * 2];
    float sn = tbl[(s * 64 + j) * 2 + 1];
    float xj   = bf2f(xs[pr][j]);
    float xj64 = bf2f(xs[pr][j + 64]);
    float x2j  = bf2f(xs[pr][2 * j]);
    float x2j1 = bf2f(xs[pr][2 * j + 1]);
    o0[j0] = (short)f2bf(xj * c - x2j1 * sn);
    o1[j0] = (short)f2bf(xj64 * c + x2j * sn);
  }
  unsigned short* xp = X + ((size_t)row * HEADS + hh) * HD;
  *(s16x8*)(xp + jb)      = o0;
  *(s16x8*)(xp + 64 + jb) = o1;
}

// ---------------- Flash attention (causal, GQA 4:1) ----------------
// grid: (SEQ/64, BATCH*NH); 4 waves x 16 q-rows; KV tile = 32
__global__ __launch_bounds__(256) void attn_fwd(
    const unsigned short* __restrict__ Q, const unsigned short* __restrict__ K,
    const unsigned short* __restrict__ V, const float* __restrict__ mask,
    unsigned short* __restrict__ O) {
  __shared__ __align__(16) unsigned short kt_[32][128];
  __shared__ __align__(16) unsigned short vt_[128][32];
  __shared__ __align__(16) unsigned short pt_[4][16][32];
  int tid = threadIdx.x, lane = tid & 63, w = tid >> 6;
  int qtile = gridDim.x - 1 - blockIdx.x;           // big tiles dispatch first
  int qbase = qtile * 64;
  int bh = blockIdx.y, b = bh >> 4, h = bh & 15, kvh = h >> 2;
  int bS = b * SEQ;
  int fr = lane & 15, kg = (lane >> 4) * 8, rg = (lane >> 4) * 4;
  int qw = qbase + w * 16;

  s16x8 aq[4];
  const unsigned short* qp = Q + ((size_t)(bS + qw + fr) * NH + h) * HD;
#pragma unroll
  for (int dc = 0; dc < 4; ++dc) aq[dc] = *(const s16x8*)(qp + dc * 32 + kg);

  f32x4 oacc[8] = {};
  float m_r[4], l_r[4];
#pragma unroll
  for (int r = 0; r < 4; ++r) { m_r[r] = -1e30f; l_r[r] = 0.f; }
  const float sc = 0.08838834764831845f;  // 1/sqrt(128)

  int ntiles = (qbase + 64) >> 5;
  for (int t7 = 0; t7 < ntiles; ++t7) {
    int kv0 = t7 * 32;
    __syncthreads();
#pragma unroll
    for (int i = 0; i < 2; ++i) {  // K tile 32x128
      int idx = tid + i * 256;
      int row = idx >> 4, seg = idx & 15;
      *(s16x8*)(&kt_[row][seg * 8]) =
          *(const s16x8*)(K + ((size_t)(bS + kv0 + row) * NKV + kvh) * HD + seg * 8);
    }
    {  // V tile transposed -> vt_[d][kv]
      int kv = tid & 31, db = (tid >> 5) * 16;
      const unsigned short* vp = V + ((size_t)(bS + kv0 + kv) * NKV + kvh) * HD + db;
      s16x8 v0 = *(const s16x8*)vp;
      s16x8 v1 = *(const s16x8*)(vp + 8);
#pragma unroll
      for (int j = 0; j < 8; ++j) { vt_[db + j][kv] = (unsigned short)v0[j]; vt_[db + 8 + j][kv] = (unsigned short)v1[j]; }
    }
    __syncthreads();

    f32x4 s0 = {}, s1 = {};
#pragma unroll
    for (int dc = 0; dc < 4; ++dc) {
      s16x8 b0 = *(const s16x8*)(&kt_[fr][dc * 32 + kg]);
      s16x8 b1 = *(const s16x8*)(&kt_[16 + fr][dc * 32 + kg]);
      s0 = MFMA16(aq[dc], b0, s0);
      s1 = MFMA16(aq[dc], b1, s1);
    }

    float pm[4];
    int c0 = kv0 + fr, c1 = kv0 + 16 + fr;
    float mv0 = mask[bS + c0], mv1 = mask[bS + c1];
#pragma unroll
    for (int r = 0; r < 4; ++r) {
      int rq = qw + rg + r;
      s0[r] = (c0 <= rq) ? s0[r] * sc + mv0 : -1e30f;
      s1[r] = (c1 <= rq) ? s1[r] * sc + mv1 : -1e30f;
      pm[r] = fmaxf(s0[r], s1[r]);
    }
#pragma unroll
    for (int off = 1; off < 16; off <<= 1)
#pragma unroll
      for (int r = 0; r < 4; ++r) pm[r] = fmaxf(pm[r], __shfl_xor(pm[r], off, 64));
    float alpha[4], rs[4];
#pragma unroll
    for (int r = 0; r < 4; ++r) {
      float mn = fmaxf(m_r[r], pm[r]);
      alpha[r] = __expf(m_r[r] - mn);
      m_r[r] = mn;
      s0[r] = __expf(s0[r] - mn);
      s1[r] = __expf(s1[r] - mn);
      rs[r] = s0[r] + s1[r];
    }
#pragma unroll
    for (int off = 1; off < 16; off <<= 1)
#pragma unroll
      for (int r = 0; r < 4; ++r) rs[r] += __shfl_xor(rs[r], off, 64);
#pragma unroll
    for (int r = 0; r < 4; ++r) l_r[r] = l_r[r] * alpha[r] + rs[r];
#pragma unroll
    for (int o = 0; o < 8; ++o)
#pragma unroll
      for (int r = 0; r < 4; ++r) oacc[o][r] *= alpha[r];

#pragma unroll
    for (int r = 0; r < 4; ++r) {  // P -> LDS (per-wave)
      pt_[w][rg + r][fr]      = f2bf(s0[r]);
      pt_[w][rg + r][16 + fr] = f2bf(s1[r]);
    }
    s16x8 ap = *(const s16x8*)(&pt_[w][fr][kg]);
#pragma unroll
    for (int o = 0; o < 8; ++o) {
      s16x8 bv = *(const s16x8*)(&vt_[o * 16 + fr][kg]);
      oacc[o] = MFMA16(ap, bv, oacc[o]);
    }
  }

  float inv[4];
#pragma unroll
  for (int r = 0; r < 4; ++r) inv[r] = 1.0f / l_r[r];
  unsigned short* op = O + (size_t)(bS + qw + rg) * (NH * HD) + h * HD;
#pragma unroll
  for (int o = 0; o < 8; ++o)
#pragma unroll
    for (int r = 0; r < 4; ++r)
      op[(size_t)r * (NH * HD) + o * 16 + fr] = f2bf(oacc[o][r] * inv[r]);
}

extern "C" void kernel_launch(void* const* d_in, const int* in_sizes, int n_in,
                              void* d_out, int out_size, void* d_ws, size_t ws_size,
                              hipStream_t stream) {
  const float* hidden = (const float*)d_in[0];
  const float* mask   = (const float*)d_in[1];
  const float* Wq     = (const float*)d_in[2];
  const float* Wk     = (const float*)d_in[3];
  const float* Wv     = (const float*)d_in[4];
  const float* Wo     = (const float*)d_in[5];
  float* out = (float*)d_out;

  char* ws = (char*)d_ws;
  unsigned short* BT  = (unsigned short*)(ws);                 // 3072x2048 bf16 = 12.58 MB
  unsigned short* WoT = (unsigned short*)(ws + 12582912);      // 2048x2048 bf16 =  8.39 MB
  unsigned short* Qb  = (unsigned short*)(ws + 20971520);      // 4096x2048 bf16 = 16.78 MB
  unsigned short* Kb  = (unsigned short*)(ws + 37748736);      // 4096x512  bf16 =  4.19 MB
  unsigned short* Vb  = (unsigned short*)(ws + 41943040);      // 4096x512  bf16 =  4.19 MB
  unsigned short* AO  = (unsigned short*)(ws + 46137344);      // 4096x2048 bf16 = 16.78 MB
  float*          tbl = (float*)(ws + 62914560);               // 2048x64x2 f32  =  1.05 MB

  transpose_convert<<<dim3(64, 64), 256, 0, stream>>>(Wq, BT, KDIM, 2048);
  transpose_convert<<<dim3(16, 64), 256, 0, stream>>>(Wk, BT + (size_t)2048 * KDIM, KDIM, 512);
  transpose_convert<<<dim3(16, 64), 256, 0, stream>>>(Wv, BT + (size_t)2560 * KDIM, KDIM, 512);
  transpose_convert<<<dim3(64, 64), 256, 0, stream>>>(Wo, WoT, KDIM, 2048);
  rope_table_kernel<<<512, 256, 0, stream>>>(tbl);

  gemm_qkv<<<dim3(NQKV / 128, MROWS / 128), 256, 0, stream>>>(hidden, BT, Qb, Kb, Vb);
  rope_kernel<<<(MROWS * NH) / 32, 256, 0, stream>>>(Qb, tbl, NH);
  rope_kernel<<<(MROWS * NKV) / 32, 256, 0, stream>>>(Kb, tbl, NKV);
  attn_fwd<<<dim3(SEQ / 64, BATCH * NH), 256, 0, stream>>>(Qb, Kb, Vb, mask, AO);
  gemm_out<<<dim3(2048 / 128, MROWS / 128), 256, 0, stream>>>(AO, WoT, out);
}

// Round 2
// 324.908 us; speedup vs baseline: 1.4846x; 1.4846x over previous
//
#include <hip/hip_runtime.h>
#include <hip/hip_bf16.h>

#define BATCH 2
#define SEQ   2048
#define NH    16
#define NKV   4
#define HD    128
#define KDIM  2048
#define MROWS 4096
#define NQKV  3072

typedef __attribute__((ext_vector_type(8))) short  s16x8;
typedef __attribute__((ext_vector_type(4))) short  s16x4;
typedef __attribute__((ext_vector_type(4))) float  f32x4;
typedef __attribute__((ext_vector_type(8))) __bf16 b16x8;

__device__ __forceinline__ unsigned short f2bf(float f) {
  __hip_bfloat16 h = __float2bfloat16(f);
  return *reinterpret_cast<unsigned short*>(&h);
}
__device__ __forceinline__ float bf2f(unsigned short h) {
  union { unsigned int u; float f; } x; x.u = ((unsigned int)h) << 16;
  return x.f;
}

__device__ __forceinline__ f32x4 MFMA16(s16x8 a, s16x8 b, f32x4 c) {
  return __builtin_amdgcn_mfma_f32_16x16x32_bf16(
      __builtin_bit_cast(b16x8, a), __builtin_bit_cast(b16x8, b), c, 0, 0, 0);
}

// ---------------- W (KxN f32) -> WT (NxK bf16) ----------------
__global__ __launch_bounds__(256) void transpose_convert(
    const float* __restrict__ W, unsigned short* __restrict__ WT, int Kd, int Nd) {
  __shared__ float tile[32][33];
  int n0 = blockIdx.x * 32, k0 = blockIdx.y * 32;
  int tx = threadIdx.x & 31, ty = threadIdx.x >> 5;
#pragma unroll
  for (int i = 0; i < 4; ++i)
    tile[ty + i * 8][tx] = W[(size_t)(k0 + ty + i * 8) * Nd + n0 + tx];
  __syncthreads();
#pragma unroll
  for (int i = 0; i < 4; ++i)
    WT[(size_t)(n0 + ty + i * 8) * Kd + k0 + tx] = f2bf(tile[tx][ty + i * 8]);
}

// ---------------- RoPE cos/sin table ----------------
__global__ __launch_bounds__(256) void rope_table_kernel(float* __restrict__ tbl) {
  int i = blockIdx.x * 256 + threadIdx.x;
  int s = i >> 6, j = i & 63;
  float inv = powf(10000.0f, -(float)(2 * j) * (1.0f / 128.0f));
  float f = (float)s * inv;
  tbl[2 * i]     = cosf(f);
  tbl[2 * i + 1] = sinf(f);
}

// ---------------- QKV GEMM; epilogue writes per-head layouts ----------------
// Qo: [B][NH][S][HD] ; Ko: [B][NKV][S][HD] ; Vo (transposed): [B][NKV][HD][S]
__global__ __launch_bounds__(256) void gemm_qkv(
    const float* __restrict__ A, const unsigned short* __restrict__ BT,
    unsigned short* __restrict__ Qo, unsigned short* __restrict__ Ko,
    unsigned short* __restrict__ Vo) {
  __shared__ __align__(16) unsigned short la[128][32];
  __shared__ __align__(16) unsigned short lb[128][32];
  int tid = threadIdx.x, lane = tid & 63, w = tid >> 6;
  int m0 = blockIdx.y * 128, n0 = blockIdx.x * 128;
  int wr = (w >> 1) * 64, wc = (w & 1) * 64;
  int fr = lane & 15, kg = (lane >> 4) * 8, rg = (lane >> 4) * 4;
  f32x4 acc[4][4] = {};
  for (int kt = 0; kt < KDIM; kt += 32) {
    __syncthreads();
#pragma unroll
    for (int i = 0; i < 4; ++i) {
      int idx = tid + i * 256;
      int row = idx >> 3, seg = idx & 7;
      float4 v = *(const float4*)(A + (size_t)(m0 + row) * KDIM + kt + seg * 4);
      s16x4 h;
      h[0] = (short)f2bf(v.x); h[1] = (short)f2bf(v.y);
      h[2] = (short)f2bf(v.z); h[3] = (short)f2bf(v.w);
      *(s16x4*)(&la[row][seg * 4]) = h;
    }
#pragma unroll
    for (int i = 0; i < 2; ++i) {
      int idx = tid + i * 256;
      int row = idx >> 2, seg = idx & 3;
      *(s16x8*)(&lb[row][seg * 8]) =
          *(const s16x8*)(BT + (size_t)(n0 + row) * KDIM + kt + seg * 8);
    }
    __syncthreads();
    s16x8 af[4], bf[4];
#pragma unroll
    for (int mi = 0; mi < 4; ++mi) af[mi] = *(const s16x8*)(&la[wr + mi * 16 + fr][kg]);
#pragma unroll
    for (int ni = 0; ni < 4; ++ni) bf[ni] = *(const s16x8*)(&lb[wc + ni * 16 + fr][kg]);
#pragma unroll
    for (int mi = 0; mi < 4; ++mi)
#pragma unroll
      for (int ni = 0; ni < 4; ++ni) acc[mi][ni] = MFMA16(af[mi], bf[ni], acc[mi][ni]);
  }
  int rbase = m0 + wr + rg;
#pragma unroll
  for (int ni = 0; ni < 4; ++ni) {
    int gn = n0 + wc + ni * 16 + fr;
    if (gn < 2048) {
      int hh = gn >> 7, d = gn & 127;
#pragma unroll
      for (int mi = 0; mi < 4; ++mi)
#pragma unroll
        for (int r = 0; r < 4; ++r) {
          int grow = rbase + mi * 16 + r;
          int bb = grow >> 11, ss = grow & 2047;
          Qo[((size_t)(bb * NH + hh) * SEQ + ss) * HD + d] = f2bf(acc[mi][ni][r]);
        }
    } else if (gn < 2560) {
      int c = gn - 2048, kvh = c >> 7, d = c & 127;
#pragma unroll
      for (int mi = 0; mi < 4; ++mi)
#pragma unroll
        for (int r = 0; r < 4; ++r) {
          int grow = rbase + mi * 16 + r;
          int bb = grow >> 11, ss = grow & 2047;
          Ko[((size_t)(bb * NKV + kvh) * SEQ + ss) * HD + d] = f2bf(acc[mi][ni][r]);
        }
    } else {
      int c = gn - 2560, kvh = c >> 7, d = c & 127;
#pragma unroll
      for (int mi = 0; mi < 4; ++mi) {
        int grow0 = rbase + mi * 16;
        int bb = grow0 >> 11, ss = grow0 & 2047;
        s16x4 pk;
#pragma unroll
        for (int r = 0; r < 4; ++r) pk[r] = (short)f2bf(acc[mi][ni][r]);
        *(s16x4*)(Vo + ((size_t)(bb * NKV + kvh) * HD + d) * SEQ + ss) = pk;
      }
    }
  }
}

// ---------------- O-proj GEMM ----------------
__global__ __launch_bounds__(256) void gemm_out(
    const unsigned short* __restrict__ A, const unsigned short* __restrict__ BT,
    float* __restrict__ C) {
  __shared__ __align__(16) unsigned short la[128][32];
  __shared__ __align__(16) unsigned short lb[128][32];
  int tid = threadIdx.x, lane = tid & 63, w = tid >> 6;
  int m0 = blockIdx.y * 128, n0 = blockIdx.x * 128;
  int wr = (w >> 1) * 64, wc = (w & 1) * 64;
  int fr = lane & 15, kg = (lane >> 4) * 8, rg = (lane >> 4) * 4;
  f32x4 acc[4][4] = {};
  for (int kt = 0; kt < KDIM; kt += 32) {
    __syncthreads();
#pragma unroll
    for (int i = 0; i < 2; ++i) {
      int idx = tid + i * 256;
      int row = idx >> 2, seg = idx & 3;
      *(s16x8*)(&la[row][seg * 8]) =
          *(const s16x8*)(A + (size_t)(m0 + row) * KDIM + kt + seg * 8);
      *(s16x8*)(&lb[row][seg * 8]) =
          *(const s16x8*)(BT + (size_t)(n0 + row) * KDIM + kt + seg * 8);
    }
    __syncthreads();
    s16x8 af[4], bf[4];
#pragma unroll
    for (int mi = 0; mi < 4; ++mi) af[mi] = *(const s16x8*)(&la[wr + mi * 16 + fr][kg]);
#pragma unroll
    for (int ni = 0; ni < 4; ++ni) bf[ni] = *(const s16x8*)(&lb[wc + ni * 16 + fr][kg]);
#pragma unroll
    for (int mi = 0; mi < 4; ++mi)
#pragma unroll
      for (int ni = 0; ni < 4; ++ni) acc[mi][ni] = MFMA16(af[mi], bf[ni], acc[mi][ni]);
  }
  int rbase = m0 + wr + rg;
#pragma unroll
  for (int ni = 0; ni < 4; ++ni) {
    int gn = n0 + wc + ni * 16 + fr;
#pragma unroll
    for (int mi = 0; mi < 4; ++mi)
#pragma unroll
      for (int r = 0; r < 4; ++r)
        C[(size_t)(rbase + mi * 16 + r) * 2048 + gn] = acc[mi][ni][r];
  }
}

// ---------------- RoPE on [rows][128] contiguous layout ----------------
__global__ __launch_bounds__(256) void rope2(
    unsigned short* __restrict__ X, const float* __restrict__ tbl) {
  __shared__ __align__(16) unsigned short xs[32][136];
  int tid = threadIdx.x;
  size_t r0 = (size_t)blockIdx.x * 32;
#pragma unroll
  for (int i = 0; i < 2; ++i) {
    int idx = tid + i * 256;
    int pr = idx >> 4, seg = idx & 15;
    *(s16x8*)(&xs[pr][seg * 8]) = *(const s16x8*)(X + (r0 + pr) * 128 + seg * 8);
  }
  __syncthreads();
  int pr = tid >> 3, jb = (tid & 7) * 8;
  size_t row = r0 + pr;
  int s = (int)(row & (SEQ - 1));
  s16x8 o0, o1;
#pragma unroll
  for (int j0 = 0; j0 < 8; ++j0) {
    int j = jb + j0;
    float c  = tbl[(s * 64 + j) * 2];
    float sn = tbl[(s * 64 + j) * 2 + 1];
    float xj   = bf2f(xs[pr][j]);
    float xj64 = bf2f(xs[pr][j + 64]);
    float x2j  = bf2f(xs[pr][2 * j]);
    float x2j1 = bf2f(xs[pr][2 * j + 1]);
    o0[j0] = (short)f2bf(xj * c - x2j1 * sn);
    o1[j0] = (short)f2bf(xj64 * c + x2j * sn);
  }
  unsigned short* xp = X + row * 128;
  *(s16x8*)(xp + jb)      = o0;
  *(s16x8*)(xp + 64 + jb) = o1;
}

// ---------------- Flash attention (swapped QK^T, causal, GQA 4:1) ----------------
// grid: (SEQ/128, BATCH*NH); 4 waves x 32 q-rows; KV tile = 64
__global__ __launch_bounds__(256) void attn_fwd(
    const unsigned short* __restrict__ Q, const unsigned short* __restrict__ K,
    const unsigned short* __restrict__ VT, const float* __restrict__ mask,
    unsigned short* __restrict__ O) {
  __shared__ __align__(16) unsigned short kt_[64][136];
  __shared__ __align__(16) unsigned short vt_[128][72];
  __shared__ __align__(16) unsigned short pt_[4][32][40];
  int tid = threadIdx.x, lane = tid & 63, w = tid >> 6;
  int qtile = gridDim.x - 1 - blockIdx.x;
  int qbase = qtile * 128;
  int bh = blockIdx.y, b = bh >> 4, h = bh & 15, kvh = h >> 2;
  int fr = lane & 15, g = lane >> 4, kg = g * 8, rg = g * 4;
  int qw = qbase + w * 32;

  const unsigned short* Qb = Q + (size_t)(b * NH + h) * SEQ * HD;
  const unsigned short* Kb = K + (size_t)(b * NKV + kvh) * SEQ * HD;
  const unsigned short* Vb = VT + (size_t)(b * NKV + kvh) * HD * SEQ;
  const float* mb = mask + (size_t)b * SEQ;

  s16x8 aq[2][4];
#pragma unroll
  for (int nq = 0; nq < 2; ++nq)
#pragma unroll
    for (int dc = 0; dc < 4; ++dc)
      aq[nq][dc] = *(const s16x8*)(Qb + (size_t)(qw + nq * 16 + fr) * HD + dc * 32 + kg);

  f32x4 oacc[2][8] = {};
  float m_r[2] = {-1e30f, -1e30f}, l_r[2] = {0.f, 0.f};
  const float sc = 0.08838834764831845f;

  int ntiles = (qbase + 128) >> 6;
  for (int t = 0; t < ntiles; ++t) {
    int kv0 = t * 64;
    __syncthreads();
#pragma unroll
    for (int i = 0; i < 4; ++i) {  // K tile 64x128
      int idx = tid + i * 256;
      int row = idx >> 4, seg = idx & 15;
      *(s16x8*)(&kt_[row][seg * 8]) =
          *(const s16x8*)(Kb + (size_t)(kv0 + row) * HD + seg * 8);
    }
#pragma unroll
    for (int i = 0; i < 4; ++i) {  // V^T tile 128x64
      int idx = tid + i * 256;
      int row = idx >> 3, seg = idx & 7;
      *(s16x8*)(&vt_[row][seg * 8]) =
          *(const s16x8*)(Vb + (size_t)row * SEQ + kv0 + seg * 8);
    }
    __syncthreads();

    // S^T = K · Q^T : element (kv = mk*16+rg+r, q = nq*16+fr)
    f32x4 sf[4][2] = {};
#pragma unroll
    for (int mk = 0; mk < 4; ++mk) {
      s16x8 ak[4];
#pragma unroll
      for (int dc = 0; dc < 4; ++dc)
        ak[dc] = *(const s16x8*)(&kt_[mk * 16 + fr][dc * 32 + kg]);
#pragma unroll
      for (int nq = 0; nq < 2; ++nq)
#pragma unroll
        for (int dc = 0; dc < 4; ++dc)
          sf[mk][nq] = MFMA16(ak[dc], aq[nq][dc], sf[mk][nq]);
    }

    // scale + mask + causal
#pragma unroll
    for (int mk = 0; mk < 4; ++mk) {
      float4 mv = *(const float4*)(mb + kv0 + mk * 16 + rg);
      float mvr[4] = {mv.x, mv.y, mv.z, mv.w};
#pragma unroll
      for (int nq = 0; nq < 2; ++nq)
#pragma unroll
        for (int r = 0; r < 4; ++r) {
          int kv = kv0 + mk * 16 + rg + r;
          int q  = qw + nq * 16 + fr;
          float v = sf[mk][nq][r] * sc + mvr[r];
          sf[mk][nq][r] = (kv <= q) ? v : -1e30f;
        }
    }

    // online softmax per nq (row q = nq*16+fr)
#pragma unroll
    for (int nq = 0; nq < 2; ++nq) {
      float pm = -1e30f;
#pragma unroll
      for (int mk = 0; mk < 4; ++mk)
#pragma unroll
        for (int r = 0; r < 4; ++r) pm = fmaxf(pm, sf[mk][nq][r]);
      pm = fmaxf(pm, __shfl_xor(pm, 16, 64));
      pm = fmaxf(pm, __shfl_xor(pm, 32, 64));
      if (!__all(pm - m_r[nq] <= 8.0f)) {
        float mo = m_r[nq];
        float mn = fmaxf(mo, pm);
        float al = __expf(mo - mn);
        m_r[nq] = mn;
        l_r[nq] *= al;
#pragma unroll
        for (int r = 0; r < 4; ++r) {
          float ar = __shfl(al, rg + r, 16);
#pragma unroll
          for (int od = 0; od < 8; ++od) oacc[nq][od][r] *= ar;
        }
      }
      float rs = 0.f;
#pragma unroll
      for (int mk = 0; mk < 4; ++mk)
#pragma unroll
        for (int r = 0; r < 4; ++r) {
          float p = __expf(sf[mk][nq][r] - m_r[nq]);
          sf[mk][nq][r] = p;
          rs += p;
        }
      rs += __shfl_xor(rs, 16, 64);
      rs += __shfl_xor(rs, 32, 64);
      l_r[nq] += rs;
    }

    // PV in two kv-halves of 32
#pragma unroll
    for (int kk = 0; kk < 2; ++kk) {
#pragma unroll
      for (int nq = 0; nq < 2; ++nq)
#pragma unroll
        for (int mh = 0; mh < 2; ++mh) {
          int mk = kk * 2 + mh;
          s16x4 pk;
#pragma unroll
          for (int r = 0; r < 4; ++r) pk[r] = (short)f2bf(sf[mk][nq][r]);
          *(s16x4*)(&pt_[w][nq * 16 + fr][mh * 16 + rg]) = pk;
        }
      s16x8 ap[2];
#pragma unroll
      for (int nq = 0; nq < 2; ++nq)
        ap[nq] = *(const s16x8*)(&pt_[w][nq * 16 + fr][kg]);
#pragma unroll
      for (int od = 0; od < 8; ++od) {
        s16x8 bv = *(const s16x8*)(&vt_[od * 16 + fr][kk * 32 + kg]);
#pragma unroll
        for (int nq = 0; nq < 2; ++nq)
          oacc[nq][od] = MFMA16(ap[nq], bv, oacc[nq][od]);
      }
    }
  }

  // epilogue: O element (q = qw+nq*16+rg+r, d = od*16+fr)
  int bS = b * SEQ;
#pragma unroll
  for (int nq = 0; nq < 2; ++nq) {
    float iv = 1.0f / l_r[nq];
    float ivr[4];
#pragma unroll
    for (int r = 0; r < 4; ++r) ivr[r] = __shfl(iv, rg + r, 16);
#pragma unroll
    for (int r = 0; r < 4; ++r) {
      unsigned short* op = O + (size_t)(bS + qw + nq * 16 + rg + r) * 2048 + h * 128 + fr;
#pragma unroll
      for (int od = 0; od < 8; ++od)
        op[od * 16] = f2bf(oacc[nq][od][r] * ivr[r]);
    }
  }
}

extern "C" void kernel_launch(void* const* d_in, const int* in_sizes, int n_in,
                              void* d_out, int out_size, void* d_ws, size_t ws_size,
                              hipStream_t stream) {
  const float* hidden = (const float*)d_in[0];
  const float* mask   = (const float*)d_in[1];
  const float* Wq     = (const float*)d_in[2];
  const float* Wk     = (const float*)d_in[3];
  const float* Wv     = (const float*)d_in[4];
  const float* Wo     = (const float*)d_in[5];
  float* out = (float*)d_out;

  char* ws = (char*)d_ws;
  unsigned short* BT  = (unsigned short*)(ws);                 // 3072x2048 bf16
  unsigned short* WoT = (unsigned short*)(ws + 12582912);      // 2048x2048 bf16
  unsigned short* Qb  = (unsigned short*)(ws + 20971520);      // [B][NH][S][HD]
  unsigned short* Kb  = (unsigned short*)(ws + 37748736);      // [B][NKV][S][HD]
  unsigned short* VT  = (unsigned short*)(ws + 41943040);      // [B][NKV][HD][S]
  unsigned short* AO  = (unsigned short*)(ws + 46137344);      // [MROWS][2048]
  float*          tbl = (float*)(ws + 62914560);               // [S][64][2] f32

  transpose_convert<<<dim3(64, 64), 256, 0, stream>>>(Wq, BT, KDIM, 2048);
  transpose_convert<<<dim3(16, 64), 256, 0, stream>>>(Wk, BT + (size_t)2048 * KDIM, KDIM, 512);
  transpose_convert<<<dim3(16, 64), 256, 0, stream>>>(Wv, BT + (size_t)2560 * KDIM, KDIM, 512);
  transpose_convert<<<dim3(64, 64), 256, 0, stream>>>(Wo, WoT, KDIM, 2048);
  rope_table_kernel<<<512, 256, 0, stream>>>(tbl);

  gemm_qkv<<<dim3(NQKV / 128, MROWS / 128), 256, 0, stream>>>(hidden, BT, Qb, Kb, VT);
  rope2<<<(BATCH * NH * SEQ) / 32, 256, 0, stream>>>(Qb, tbl);
  rope2<<<(BATCH * NKV * SEQ) / 32, 256, 0, stream>>>(Kb, tbl);
  attn_fwd<<<dim3(SEQ / 128, BATCH * NH), 256, 0, stream>>>(Qb, Kb, VT, mask, AO);
  gemm_out<<<dim3(2048 / 128, MROWS / 128), 256, 0, stream>>>(AO, WoT, out);
}

// Round 3
// 321.367 us; speedup vs baseline: 1.5010x; 1.0110x over previous
//
#include <hip/hip_runtime.h>
#include <hip/hip_bf16.h>

#define BATCH 2
#define SEQ   2048
#define NH    16
#define NKV   4
#define HD    128
#define KDIM  2048
#define MROWS 4096
#define NQKV  3072

typedef __attribute__((ext_vector_type(8))) short  s16x8;
typedef __attribute__((ext_vector_type(4))) short  s16x4;
typedef __attribute__((ext_vector_type(4))) float  f32x4;
typedef __attribute__((ext_vector_type(8))) __bf16 b16x8;

__device__ __forceinline__ unsigned short f2bf(float f) {
  __hip_bfloat16 h = __float2bfloat16(f);
  return *reinterpret_cast<unsigned short*>(&h);
}
__device__ __forceinline__ float bf2f(unsigned short h) {
  union { unsigned int u; float f; } x; x.u = ((unsigned int)h) << 16;
  return x.f;
}

__device__ __forceinline__ f32x4 MFMA16(s16x8 a, s16x8 b, f32x4 c) {
  return __builtin_amdgcn_mfma_f32_16x16x32_bf16(
      __builtin_bit_cast(b16x8, a), __builtin_bit_cast(b16x8, b), c, 0, 0, 0);
}

__device__ __forceinline__ void gload_lds16(const void* g, void* lds) {
  __builtin_amdgcn_global_load_lds(
      (const __attribute__((address_space(1))) void*)g,
      (__attribute__((address_space(3))) void*)lds, 16, 0, 0);
}

// ---------------- W (KxN f32) -> WT (NxK bf16) ----------------
__global__ __launch_bounds__(256) void transpose_convert(
    const float* __restrict__ W, unsigned short* __restrict__ WT, int Kd, int Nd) {
  __shared__ float tile[32][33];
  int n0 = blockIdx.x * 32, k0 = blockIdx.y * 32;
  int tx = threadIdx.x & 31, ty = threadIdx.x >> 5;
#pragma unroll
  for (int i = 0; i < 4; ++i)
    tile[ty + i * 8][tx] = W[(size_t)(k0 + ty + i * 8) * Nd + n0 + tx];
  __syncthreads();
#pragma unroll
  for (int i = 0; i < 4; ++i)
    WT[(size_t)(n0 + ty + i * 8) * Kd + k0 + tx] = f2bf(tile[tx][ty + i * 8]);
}

// ---------------- f32 -> bf16 bulk convert ----------------
__global__ __launch_bounds__(256) void conv_bf16(
    const float* __restrict__ X, unsigned short* __restrict__ Y) {
  int i = blockIdx.x * 256 + threadIdx.x;  // one s16x8 per thread
  const float4 a = ((const float4*)X)[2 * i];
  const float4 b = ((const float4*)X)[2 * i + 1];
  s16x8 o;
  o[0] = (short)f2bf(a.x); o[1] = (short)f2bf(a.y);
  o[2] = (short)f2bf(a.z); o[3] = (short)f2bf(a.w);
  o[4] = (short)f2bf(b.x); o[5] = (short)f2bf(b.y);
  o[6] = (short)f2bf(b.z); o[7] = (short)f2bf(b.w);
  ((s16x8*)Y)[i] = o;
}

// ---------------- RoPE cos/sin table ----------------
__global__ __launch_bounds__(256) void rope_table_kernel(float* __restrict__ tbl) {
  int i = blockIdx.x * 256 + threadIdx.x;
  int s = i >> 6, j = i & 63;
  float inv = powf(10000.0f, -(float)(2 * j) * (1.0f / 128.0f));
  float f = (float)s * inv;
  tbl[2 * i]     = cosf(f);
  tbl[2 * i + 1] = sinf(f);
}

// ---------------- QKV GEMM (bf16 x bf16); per-head epilogue ----------------
__global__ __launch_bounds__(256) void gemm_qkv(
    const unsigned short* __restrict__ A, const unsigned short* __restrict__ BT,
    unsigned short* __restrict__ Qo, unsigned short* __restrict__ Ko,
    unsigned short* __restrict__ Vo) {
  __shared__ __align__(16) unsigned short la[128][32];
  __shared__ __align__(16) unsigned short lb[128][32];
  int tid = threadIdx.x, lane = tid & 63, w = tid >> 6;
  int m0 = blockIdx.y * 128, n0 = blockIdx.x * 128;
  int wr = (w >> 1) * 64, wc = (w & 1) * 64;
  int fr = lane & 15, kg = (lane >> 4) * 8, rg = (lane >> 4) * 4;
  f32x4 acc[4][4] = {};
  for (int kt = 0; kt < KDIM; kt += 32) {
    __syncthreads();
#pragma unroll
    for (int i = 0; i < 2; ++i) {
      int idx = tid + i * 256;
      int row = idx >> 2, seg = idx & 3;
      gload_lds16(A + (size_t)(m0 + row) * KDIM + kt + seg * 8,
                  (char*)la + (size_t)(i * 256 + w * 64) * 16);
      gload_lds16(BT + (size_t)(n0 + row) * KDIM + kt + seg * 8,
                  (char*)lb + (size_t)(i * 256 + w * 64) * 16);
    }
    __syncthreads();
    s16x8 af[4], bf[4];
#pragma unroll
    for (int mi = 0; mi < 4; ++mi) af[mi] = *(const s16x8*)(&la[wr + mi * 16 + fr][kg]);
#pragma unroll
    for (int ni = 0; ni < 4; ++ni) bf[ni] = *(const s16x8*)(&lb[wc + ni * 16 + fr][kg]);
#pragma unroll
    for (int mi = 0; mi < 4; ++mi)
#pragma unroll
      for (int ni = 0; ni < 4; ++ni) acc[mi][ni] = MFMA16(af[mi], bf[ni], acc[mi][ni]);
  }
  int rbase = m0 + wr + rg;
#pragma unroll
  for (int ni = 0; ni < 4; ++ni) {
    int gn = n0 + wc + ni * 16 + fr;
    if (gn < 2048) {
      int hh = gn >> 7, d = gn & 127;
#pragma unroll
      for (int mi = 0; mi < 4; ++mi)
#pragma unroll
        for (int r = 0; r < 4; ++r) {
          int grow = rbase + mi * 16 + r;
          int bb = grow >> 11, ss = grow & 2047;
          Qo[((size_t)(bb * NH + hh) * SEQ + ss) * HD + d] = f2bf(acc[mi][ni][r]);
        }
    } else if (gn < 2560) {
      int c = gn - 2048, kvh = c >> 7, d = c & 127;
#pragma unroll
      for (int mi = 0; mi < 4; ++mi)
#pragma unroll
        for (int r = 0; r < 4; ++r) {
          int grow = rbase + mi * 16 + r;
          int bb = grow >> 11, ss = grow & 2047;
          Ko[((size_t)(bb * NKV + kvh) * SEQ + ss) * HD + d] = f2bf(acc[mi][ni][r]);
        }
    } else {
      int c = gn - 2560, kvh = c >> 7, d = c & 127;
#pragma unroll
      for (int mi = 0; mi < 4; ++mi) {
        int grow0 = rbase + mi * 16;
        int bb = grow0 >> 11, ss = grow0 & 2047;
        s16x4 pk;
#pragma unroll
        for (int r = 0; r < 4; ++r) pk[r] = (short)f2bf(acc[mi][ni][r]);
        *(s16x4*)(Vo + ((size_t)(bb * NKV + kvh) * HD + d) * SEQ + ss) = pk;
      }
    }
  }
}

// ---------------- O-proj GEMM ----------------
__global__ __launch_bounds__(256) void gemm_out(
    const unsigned short* __restrict__ A, const unsigned short* __restrict__ BT,
    float* __restrict__ C) {
  __shared__ __align__(16) unsigned short la[128][32];
  __shared__ __align__(16) unsigned short lb[128][32];
  int tid = threadIdx.x, lane = tid & 63, w = tid >> 6;
  int m0 = blockIdx.y * 128, n0 = blockIdx.x * 128;
  int wr = (w >> 1) * 64, wc = (w & 1) * 64;
  int fr = lane & 15, kg = (lane >> 4) * 8, rg = (lane >> 4) * 4;
  f32x4 acc[4][4] = {};
  for (int kt = 0; kt < KDIM; kt += 32) {
    __syncthreads();
#pragma unroll
    for (int i = 0; i < 2; ++i) {
      int idx = tid + i * 256;
      int row = idx >> 2, seg = idx & 3;
      gload_lds16(A + (size_t)(m0 + row) * KDIM + kt + seg * 8,
                  (char*)la + (size_t)(i * 256 + w * 64) * 16);
      gload_lds16(BT + (size_t)(n0 + row) * KDIM + kt + seg * 8,
                  (char*)lb + (size_t)(i * 256 + w * 64) * 16);
    }
    __syncthreads();
    s16x8 af[4], bf[4];
#pragma unroll
    for (int mi = 0; mi < 4; ++mi) af[mi] = *(const s16x8*)(&la[wr + mi * 16 + fr][kg]);
#pragma unroll
    for (int ni = 0; ni < 4; ++ni) bf[ni] = *(const s16x8*)(&lb[wc + ni * 16 + fr][kg]);
#pragma unroll
    for (int mi = 0; mi < 4; ++mi)
#pragma unroll
      for (int ni = 0; ni < 4; ++ni) acc[mi][ni] = MFMA16(af[mi], bf[ni], acc[mi][ni]);
  }
  int rbase = m0 + wr + rg;
#pragma unroll
  for (int ni = 0; ni < 4; ++ni) {
    int gn = n0 + wc + ni * 16 + fr;
#pragma unroll
    for (int mi = 0; mi < 4; ++mi)
#pragma unroll
      for (int r = 0; r < 4; ++r)
        C[(size_t)(rbase + mi * 16 + r) * 2048 + gn] = acc[mi][ni][r];
  }
}

// ---------------- RoPE on [rows][128] contiguous layout ----------------
__global__ __launch_bounds__(256) void rope2(
    unsigned short* __restrict__ X, const float* __restrict__ tbl) {
  __shared__ __align__(16) unsigned short xs[32][136];
  int tid = threadIdx.x;
  size_t r0 = (size_t)blockIdx.x * 32;
#pragma unroll
  for (int i = 0; i < 2; ++i) {
    int idx = tid + i * 256;
    int pr = idx >> 4, seg = idx & 15;
    *(s16x8*)(&xs[pr][seg * 8]) = *(const s16x8*)(X + (r0 + pr) * 128 + seg * 8);
  }
  __syncthreads();
  int pr = tid >> 3, jb = (tid & 7) * 8;
  size_t row = r0 + pr;
  int s = (int)(row & (SEQ - 1));
  s16x8 o0, o1;
#pragma unroll
  for (int j0 = 0; j0 < 8; ++j0) {
    int j = jb + j0;
    float c  = tbl[(s * 64 + j) * 2];
    float sn = tbl[(s * 64 + j) * 2 + 1];
    float xj   = bf2f(xs[pr][j]);
    float xj64 = bf2f(xs[pr][j + 64]);
    float x2j  = bf2f(xs[pr][2 * j]);
    float x2j1 = bf2f(xs[pr][2 * j + 1]);
    o0[j0] = (short)f2bf(xj * c - x2j1 * sn);
    o1[j0] = (short)f2bf(xj64 * c + x2j * sn);
  }
  unsigned short* xp = X + row * 128;
  *(s16x8*)(xp + jb)      = o0;
  *(s16x8*)(xp + 64 + jb) = o1;
}

// ---------------- Flash attention: 1 wave / 32 q-rows, no barriers ----------------
// grid: (SEQ/32 * BATCH*NH) flat in x; XCD-swizzled mapping
__global__ __launch_bounds__(64, 2) void attn_fwd(
    const unsigned short* __restrict__ Q, const unsigned short* __restrict__ K,
    const unsigned short* __restrict__ VT, const float* __restrict__ mask,
    unsigned short* __restrict__ O) {
  __shared__ __align__(16) unsigned short pt_[32][36];
  int lane = threadIdx.x;
  // swizzle: XCD (linear%8) owns one (b,kvh) group of 4 heads
  int linear = blockIdx.x;
  int g8 = linear & 7, rest = linear >> 3;
  int bh = g8 * 4 + (rest & 3);
  int qt = rest >> 2;                 // 0..63
  int qbase = qt * 32;
  int b = bh >> 4, h = bh & 15, kvh = h >> 2;
  int fr = lane & 15, g = lane >> 4, kg = g * 8, rg = g * 4;

  const unsigned short* Qb = Q + (size_t)(b * NH + h) * SEQ * HD;
  const unsigned short* Kb = K + (size_t)(b * NKV + kvh) * SEQ * HD;
  const unsigned short* Vb = VT + (size_t)(b * NKV + kvh) * HD * SEQ;
  const float* mb = mask + (size_t)b * SEQ;

  s16x8 aq[2][4];
#pragma unroll
  for (int nq = 0; nq < 2; ++nq)
#pragma unroll
    for (int dc = 0; dc < 4; ++dc)
      aq[nq][dc] = *(const s16x8*)(Qb + (size_t)(qbase + nq * 16 + fr) * HD + dc * 32 + kg);

  f32x4 oacc[2][8] = {};
  float m_r[2] = {-3e38f, -3e38f}, l_r[2] = {0.f, 0.f};
  const float sc = 0.08838834764831845f;

  for (int kv0 = 0; kv0 <= qbase; kv0 += 32) {
    // S^T = K . Q^T  (kv = mk*16+rg+r rows, q = nq*16+fr cols)
    f32x4 sf[2][2] = {};
    __builtin_amdgcn_s_setprio(1);
#pragma unroll
    for (int mk = 0; mk < 2; ++mk) {
      s16x8 ak[4];
#pragma unroll
      for (int dc = 0; dc < 4; ++dc)
        ak[dc] = *(const s16x8*)(Kb + (size_t)(kv0 + mk * 16 + fr) * HD + dc * 32 + kg);
#pragma unroll
      for (int nq = 0; nq < 2; ++nq)
#pragma unroll
        for (int dc = 0; dc < 4; ++dc)
          sf[mk][nq] = MFMA16(ak[dc], aq[nq][dc], sf[mk][nq]);
    }
    __builtin_amdgcn_s_setprio(0);

    // scale + mask + causal
#pragma unroll
    for (int mk = 0; mk < 2; ++mk) {
      float4 mv = *(const float4*)(mb + kv0 + mk * 16 + rg);
      float mvr[4] = {mv.x, mv.y, mv.z, mv.w};
#pragma unroll
      for (int nq = 0; nq < 2; ++nq)
#pragma unroll
        for (int r = 0; r < 4; ++r) {
          int kv = kv0 + mk * 16 + rg + r;
          int q  = qbase + nq * 16 + fr;
          float v = sf[mk][nq][r] * sc + mvr[r];
          sf[mk][nq][r] = (kv <= q) ? v : -3e38f;
        }
    }

    // online softmax per nq (lane's row q = nq*16+fr)
#pragma unroll
    for (int nq = 0; nq < 2; ++nq) {
      float pm = -3e38f;
#pragma unroll
      for (int mk = 0; mk < 2; ++mk)
#pragma unroll
        for (int r = 0; r < 4; ++r) pm = fmaxf(pm, sf[mk][nq][r]);
      pm = fmaxf(pm, __shfl_xor(pm, 16, 64));
      pm = fmaxf(pm, __shfl_xor(pm, 32, 64));
      if (!__all(pm - m_r[nq] <= 8.0f)) {
        float mo = m_r[nq];
        float mn = fmaxf(mo, pm);
        float al = __expf(mo - mn);
        m_r[nq] = mn;
        l_r[nq] *= al;
#pragma unroll
        for (int r = 0; r < 4; ++r) {
          float ar = __shfl(al, rg + r, 16);
#pragma unroll
          for (int od = 0; od < 8; ++od) oacc[nq][od][r] *= ar;
        }
      }
      float rs = 0.f;
#pragma unroll
      for (int mk = 0; mk < 2; ++mk)
#pragma unroll
        for (int r = 0; r < 4; ++r) {
          float p = __expf(sf[mk][nq][r] - m_r[nq]);
          sf[mk][nq][r] = p;
          rs += p;
        }
      rs += __shfl_xor(rs, 16, 64);
      rs += __shfl_xor(rs, 32, 64);
      l_r[nq] += rs;
    }

    // P repack (same-wave LDS, no barrier) + PV
#pragma unroll
    for (int nq = 0; nq < 2; ++nq)
#pragma unroll
      for (int mk = 0; mk < 2; ++mk) {
        s16x4 pk;
#pragma unroll
        for (int r = 0; r < 4; ++r) pk[r] = (short)f2bf(sf[mk][nq][r]);
        *(s16x4*)(&pt_[nq * 16 + fr][mk * 16 + rg]) = pk;
      }
    s16x8 ap[2];
#pragma unroll
    for (int nq = 0; nq < 2; ++nq)
      ap[nq] = *(const s16x8*)(&pt_[nq * 16 + fr][kg]);
    __builtin_amdgcn_s_setprio(1);
#pragma unroll
    for (int od = 0; od < 8; ++od) {
      s16x8 bv = *(const s16x8*)(Vb + (size_t)(od * 16 + fr) * SEQ + kv0 + kg);
#pragma unroll
      for (int nq = 0; nq < 2; ++nq)
        oacc[nq][od] = MFMA16(ap[nq], bv, oacc[nq][od]);
    }
    __builtin_amdgcn_s_setprio(0);
  }

  // epilogue: O element (q = qbase+nq*16+rg+r, d = od*16+fr)
  int bS = b * SEQ;
#pragma unroll
  for (int nq = 0; nq < 2; ++nq) {
    float iv = 1.0f / l_r[nq];
    float ivr[4];
#pragma unroll
    for (int r = 0; r < 4; ++r) ivr[r] = __shfl(iv, rg + r, 16);
#pragma unroll
    for (int r = 0; r < 4; ++r) {
      unsigned short* op = O + (size_t)(bS + qbase + nq * 16 + rg + r) * 2048 + h * 128 + fr;
#pragma unroll
      for (int od = 0; od < 8; ++od)
        op[od * 16] = f2bf(oacc[nq][od][r] * ivr[r]);
    }
  }
}

extern "C" void kernel_launch(void* const* d_in, const int* in_sizes, int n_in,
                              void* d_out, int out_size, void* d_ws, size_t ws_size,
                              hipStream_t stream) {
  const float* hidden = (const float*)d_in[0];
  const float* mask   = (const float*)d_in[1];
  const float* Wq     = (const float*)d_in[2];
  const float* Wk     = (const float*)d_in[3];
  const float* Wv     = (const float*)d_in[4];
  const float* Wo     = (const float*)d_in[5];
  float* out = (float*)d_out;

  char* ws = (char*)d_ws;
  unsigned short* BT  = (unsigned short*)(ws);                 // 3072x2048 bf16
  unsigned short* WoT = (unsigned short*)(ws + 12582912);      // 2048x2048 bf16
  unsigned short* Qb  = (unsigned short*)(ws + 20971520);      // [B][NH][S][HD]
  unsigned short* Kb  = (unsigned short*)(ws + 37748736);      // [B][NKV][S][HD]
  unsigned short* VT  = (unsigned short*)(ws + 41943040);      // [B][NKV][HD][S]
  unsigned short* AO  = (unsigned short*)(ws + 46137344);      // [MROWS][2048] bf16
  float*          tbl = (float*)(ws + 62914560);               // [S][64][2] f32
  unsigned short* Ab  = AO;  // hidden as bf16; dead before attn writes AO

  conv_bf16<<<MROWS * KDIM / (256 * 8), 256, 0, stream>>>(hidden, Ab);
  transpose_convert<<<dim3(64, 64), 256, 0, stream>>>(Wq, BT, KDIM, 2048);
  transpose_convert<<<dim3(16, 64), 256, 0, stream>>>(Wk, BT + (size_t)2048 * KDIM, KDIM, 512);
  transpose_convert<<<dim3(16, 64), 256, 0, stream>>>(Wv, BT + (size_t)2560 * KDIM, KDIM, 512);
  transpose_convert<<<dim3(64, 64), 256, 0, stream>>>(Wo, WoT, KDIM, 2048);
  rope_table_kernel<<<512, 256, 0, stream>>>(tbl);

  gemm_qkv<<<dim3(NQKV / 128, MROWS / 128), 256, 0, stream>>>(Ab, BT, Qb, Kb, VT);
  rope2<<<(BATCH * NH * SEQ) / 32, 256, 0, stream>>>(Qb, tbl);
  rope2<<<(BATCH * NKV * SEQ) / 32, 256, 0, stream>>>(Kb, tbl);
  attn_fwd<<<dim3((SEQ / 32) * BATCH * NH), 64, 0, stream>>>(Qb, Kb, VT, mask, AO);
  gemm_out<<<dim3(2048 / 128, MROWS / 128), 256, 0, stream>>>(AO, WoT, out);
}

// Round 4
// 234.632 us; speedup vs baseline: 2.0559x; 1.3697x over previous
//
#include <hip/hip_runtime.h>
#include <hip/hip_bf16.h>

#define BATCH 2
#define SEQ   2048
#define NH    16
#define NKV   4
#define HD    128
#define KDIM  2048
#define MROWS 4096
#define NQKV  3072

typedef __attribute__((ext_vector_type(8))) short  s16x8;
typedef __attribute__((ext_vector_type(4))) short  s16x4;
typedef __attribute__((ext_vector_type(4))) float  f32x4;
typedef __attribute__((ext_vector_type(8))) __bf16 b16x8;

__device__ __forceinline__ unsigned short f2bf(float f) {
  __hip_bfloat16 h = __float2bfloat16(f);
  return *reinterpret_cast<unsigned short*>(&h);
}
__device__ __forceinline__ float bf2f(unsigned short h) {
  union { unsigned int u; float f; } x; x.u = ((unsigned int)h) << 16;
  return x.f;
}

__device__ __forceinline__ f32x4 MFMA16(s16x8 a, s16x8 b, f32x4 c) {
  return __builtin_amdgcn_mfma_f32_16x16x32_bf16(
      __builtin_bit_cast(b16x8, a), __builtin_bit_cast(b16x8, b), c, 0, 0, 0);
}

__device__ __forceinline__ void gload_lds16(const void* g, void* lds) {
  __builtin_amdgcn_global_load_lds(
      (const __attribute__((address_space(1))) void*)g,
      (__attribute__((address_space(3))) void*)lds, 16, 0, 0);
}

// ---------------- W (KxN f32) -> WT (NxK bf16) ----------------
__global__ __launch_bounds__(256) void transpose_convert(
    const float* __restrict__ W, unsigned short* __restrict__ WT, int Kd, int Nd) {
  __shared__ float tile[32][33];
  int n0 = blockIdx.x * 32, k0 = blockIdx.y * 32;
  int tx = threadIdx.x & 31, ty = threadIdx.x >> 5;
#pragma unroll
  for (int i = 0; i < 4; ++i)
    tile[ty + i * 8][tx] = W[(size_t)(k0 + ty + i * 8) * Nd + n0 + tx];
  __syncthreads();
#pragma unroll
  for (int i = 0; i < 4; ++i)
    WT[(size_t)(n0 + ty + i * 8) * Kd + k0 + tx] = f2bf(tile[tx][ty + i * 8]);
}

// ---------------- f32 -> bf16 bulk convert ----------------
__global__ __launch_bounds__(256) void conv_bf16(
    const float* __restrict__ X, unsigned short* __restrict__ Y) {
  int i = blockIdx.x * 256 + threadIdx.x;
  const float4 a = ((const float4*)X)[2 * i];
  const float4 b = ((const float4*)X)[2 * i + 1];
  s16x8 o;
  o[0] = (short)f2bf(a.x); o[1] = (short)f2bf(a.y);
  o[2] = (short)f2bf(a.z); o[3] = (short)f2bf(a.w);
  o[4] = (short)f2bf(b.x); o[5] = (short)f2bf(b.y);
  o[6] = (short)f2bf(b.z); o[7] = (short)f2bf(b.w);
  ((s16x8*)Y)[i] = o;
}

// ---------------- RoPE cos/sin table ----------------
__global__ __launch_bounds__(256) void rope_table_kernel(float* __restrict__ tbl) {
  int i = blockIdx.x * 256 + threadIdx.x;
  int s = i >> 6, j = i & 63;
  float inv = powf(10000.0f, -(float)(2 * j) * (1.0f / 128.0f));
  float f = (float)s * inv;
  tbl[2 * i]     = cosf(f);
  tbl[2 * i + 1] = sinf(f);
}

// ---------------- QKV GEMM (bf16 x bf16); per-head epilogue ----------------
__global__ __launch_bounds__(256) void gemm_qkv(
    const unsigned short* __restrict__ A, const unsigned short* __restrict__ BT,
    unsigned short* __restrict__ Qo, unsigned short* __restrict__ Ko,
    unsigned short* __restrict__ Vo) {
  __shared__ __align__(16) unsigned short la[128][32];
  __shared__ __align__(16) unsigned short lb[128][32];
  int tid = threadIdx.x, lane = tid & 63, w = tid >> 6;
  int m0 = blockIdx.y * 128, n0 = blockIdx.x * 128;
  int wr = (w >> 1) * 64, wc = (w & 1) * 64;
  int fr = lane & 15, kg = (lane >> 4) * 8, rg = (lane >> 4) * 4;
  f32x4 acc[4][4] = {};
  for (int kt = 0; kt < KDIM; kt += 32) {
    __syncthreads();
#pragma unroll
    for (int i = 0; i < 2; ++i) {
      int idx = tid + i * 256;
      int row = idx >> 2, seg = idx & 3;
      gload_lds16(A + (size_t)(m0 + row) * KDIM + kt + seg * 8,
                  (char*)la + (size_t)(i * 256 + w * 64) * 16);
      gload_lds16(BT + (size_t)(n0 + row) * KDIM + kt + seg * 8,
                  (char*)lb + (size_t)(i * 256 + w * 64) * 16);
    }
    __syncthreads();
    s16x8 af[4], bf[4];
#pragma unroll
    for (int mi = 0; mi < 4; ++mi) af[mi] = *(const s16x8*)(&la[wr + mi * 16 + fr][kg]);
#pragma unroll
    for (int ni = 0; ni < 4; ++ni) bf[ni] = *(const s16x8*)(&lb[wc + ni * 16 + fr][kg]);
#pragma unroll
    for (int mi = 0; mi < 4; ++mi)
#pragma unroll
      for (int ni = 0; ni < 4; ++ni) acc[mi][ni] = MFMA16(af[mi], bf[ni], acc[mi][ni]);
  }
  int rbase = m0 + wr + rg;
#pragma unroll
  for (int ni = 0; ni < 4; ++ni) {
    int gn = n0 + wc + ni * 16 + fr;
    if (gn < 2048) {
      int hh = gn >> 7, d = gn & 127;
#pragma unroll
      for (int mi = 0; mi < 4; ++mi)
#pragma unroll
        for (int r = 0; r < 4; ++r) {
          int grow = rbase + mi * 16 + r;
          int bb = grow >> 11, ss = grow & 2047;
          Qo[((size_t)(bb * NH + hh) * SEQ + ss) * HD + d] = f2bf(acc[mi][ni][r]);
        }
    } else if (gn < 2560) {
      int c = gn - 2048, kvh = c >> 7, d = c & 127;
#pragma unroll
      for (int mi = 0; mi < 4; ++mi)
#pragma unroll
        for (int r = 0; r < 4; ++r) {
          int grow = rbase + mi * 16 + r;
          int bb = grow >> 11, ss = grow & 2047;
          Ko[((size_t)(bb * NKV + kvh) * SEQ + ss) * HD + d] = f2bf(acc[mi][ni][r]);
        }
    } else {
      int c = gn - 2560, kvh = c >> 7, d = c & 127;
#pragma unroll
      for (int mi = 0; mi < 4; ++mi) {
        int grow0 = rbase + mi * 16;
        int bb = grow0 >> 11, ss = grow0 & 2047;
        s16x4 pk;
#pragma unroll
        for (int r = 0; r < 4; ++r) pk[r] = (short)f2bf(acc[mi][ni][r]);
        *(s16x4*)(Vo + ((size_t)(bb * NKV + kvh) * HD + d) * SEQ + ss) = pk;
      }
    }
  }
}

// ---------------- O-proj GEMM ----------------
__global__ __launch_bounds__(256) void gemm_out(
    const unsigned short* __restrict__ A, const unsigned short* __restrict__ BT,
    float* __restrict__ C) {
  __shared__ __align__(16) unsigned short la[128][32];
  __shared__ __align__(16) unsigned short lb[128][32];
  int tid = threadIdx.x, lane = tid & 63, w = tid >> 6;
  int m0 = blockIdx.y * 128, n0 = blockIdx.x * 128;
  int wr = (w >> 1) * 64, wc = (w & 1) * 64;
  int fr = lane & 15, kg = (lane >> 4) * 8, rg = (lane >> 4) * 4;
  f32x4 acc[4][4] = {};
  for (int kt = 0; kt < KDIM; kt += 32) {
    __syncthreads();
#pragma unroll
    for (int i = 0; i < 2; ++i) {
      int idx = tid + i * 256;
      int row = idx >> 2, seg = idx & 3;
      gload_lds16(A + (size_t)(m0 + row) * KDIM + kt + seg * 8,
                  (char*)la + (size_t)(i * 256 + w * 64) * 16);
      gload_lds16(BT + (size_t)(n0 + row) * KDIM + kt + seg * 8,
                  (char*)lb + (size_t)(i * 256 + w * 64) * 16);
    }
    __syncthreads();
    s16x8 af[4], bf[4];
#pragma unroll
    for (int mi = 0; mi < 4; ++mi) af[mi] = *(const s16x8*)(&la[wr + mi * 16 + fr][kg]);
#pragma unroll
    for (int ni = 0; ni < 4; ++ni) bf[ni] = *(const s16x8*)(&lb[wc + ni * 16 + fr][kg]);
#pragma unroll
    for (int mi = 0; mi < 4; ++mi)
#pragma unroll
      for (int ni = 0; ni < 4; ++ni) acc[mi][ni] = MFMA16(af[mi], bf[ni], acc[mi][ni]);
  }
  int rbase = m0 + wr + rg;
#pragma unroll
  for (int ni = 0; ni < 4; ++ni) {
    int gn = n0 + wc + ni * 16 + fr;
#pragma unroll
    for (int mi = 0; mi < 4; ++mi)
#pragma unroll
      for (int r = 0; r < 4; ++r)
        C[(size_t)(rbase + mi * 16 + r) * 2048 + gn] = acc[mi][ni][r];
  }
}

// ---------------- RoPE on [rows][128] contiguous layout ----------------
__global__ __launch_bounds__(256) void rope2(
    unsigned short* __restrict__ X, const float* __restrict__ tbl) {
  __shared__ __align__(16) unsigned short xs[32][136];
  int tid = threadIdx.x;
  size_t r0 = (size_t)blockIdx.x * 32;
#pragma unroll
  for (int i = 0; i < 2; ++i) {
    int idx = tid + i * 256;
    int pr = idx >> 4, seg = idx & 15;
    *(s16x8*)(&xs[pr][seg * 8]) = *(const s16x8*)(X + (r0 + pr) * 128 + seg * 8);
  }
  __syncthreads();
  int pr = tid >> 3, jb = (tid & 7) * 8;
  size_t row = r0 + pr;
  int s = (int)(row & (SEQ - 1));
  s16x8 o0, o1;
#pragma unroll
  for (int j0 = 0; j0 < 8; ++j0) {
    int j = jb + j0;
    float c  = tbl[(s * 64 + j) * 2];
    float sn = tbl[(s * 64 + j) * 2 + 1];
    float xj   = bf2f(xs[pr][j]);
    float xj64 = bf2f(xs[pr][j + 64]);
    float x2j  = bf2f(xs[pr][2 * j]);
    float x2j1 = bf2f(xs[pr][2 * j + 1]);
    o0[j0] = (short)f2bf(xj * c - x2j1 * sn);
    o1[j0] = (short)f2bf(xj64 * c + x2j * sn);
  }
  unsigned short* xp = X + row * 128;
  *(s16x8*)(xp + jb)      = o0;
  *(s16x8*)(xp + 64 + jb) = o1;
}

// ---------------- Flash attention v4: 4 waves, K dbuf, async reg-staging ----------------
// 1D grid, 512 blocks: XCD x owns (b,kvh) group x; big q-tiles dispatch first.
__global__ __launch_bounds__(256, 2) void attn_fwd(
    const unsigned short* __restrict__ Q, const unsigned short* __restrict__ K,
    const unsigned short* __restrict__ VT, const float* __restrict__ mask,
    unsigned short* __restrict__ O) {
  __shared__ __align__(16) unsigned short kt_[2][64][136];
  __shared__ __align__(16) unsigned short vt_[128][72];
  __shared__ __align__(16) unsigned short pt_[4][32][40];

  int tid = threadIdx.x, lane = tid & 63, w = tid >> 6;
  int l = blockIdx.x;
  int grp = l & 7, slot = l >> 3;
  int hloc = slot & 3, qt = 15 - (slot >> 2);
  int b = grp >> 2, kvh = grp & 3, h = kvh * 4 + hloc;
  int qbase = qt * 128;
  int fr = lane & 15, g = lane >> 4, kg = g * 8, rg = g * 4;
  int qw = qbase + w * 32;

  const unsigned short* Qb = Q + (size_t)(b * NH + h) * SEQ * HD;
  const unsigned short* Kb = K + (size_t)(b * NKV + kvh) * SEQ * HD;
  const unsigned short* Vb = VT + (size_t)(b * NKV + kvh) * HD * SEQ;
  const float* mb = mask + (size_t)b * SEQ;

  s16x8 aq[2][4];
#pragma unroll
  for (int nq = 0; nq < 2; ++nq)
#pragma unroll
    for (int dc = 0; dc < 4; ++dc)
      aq[nq][dc] = *(const s16x8*)(Qb + (size_t)(qw + nq * 16 + fr) * HD + dc * 32 + kg);

  // staging geometry: K rows krow+i*16, 16B chunk kpos; V chunks tid+256*i
  int krow = tid >> 4, kpos = (tid & 15) * 8;

  f32x4 oacc[2][8] = {};
  float m_r[2] = {-3e38f, -3e38f}, l_r[2] = {0.f, 0.f};
  const float sc = 0.08838834764831845f;
  int ntiles = 2 * qt + 2;

  s16x8 kreg[4], vreg[4];
  // prologue: issue K(0), V(0); write K(0)
#pragma unroll
  for (int i = 0; i < 4; ++i)
    kreg[i] = *(const s16x8*)(Kb + (size_t)(krow + i * 16) * HD + kpos);
#pragma unroll
  for (int i = 0; i < 4; ++i) {
    int c = tid + 256 * i;
    vreg[i] = *(const s16x8*)(Vb + (size_t)(c >> 3) * SEQ + (c & 7) * 8);
  }
#pragma unroll
  for (int i = 0; i < 4; ++i)
    *(s16x8*)(&kt_[0][krow + i * 16][kpos]) = kreg[i];
  __syncthreads();

  int cur = 0;
  for (int t = 0; t < ntiles; ++t) {
    int kv0 = t * 64;
    bool active = (kv0 <= qw + 31);           // wave-uniform

    // ---- phase A: write V(t); issue K(t+1); QK^T; softmax; write K(t+1) ----
#pragma unroll
    for (int i = 0; i < 4; ++i) {
      int c = tid + 256 * i;
      *(s16x8*)(&vt_[c >> 3][(c & 7) * 8]) = vreg[i];
    }
    if (t + 1 < ntiles) {
#pragma unroll
      for (int i = 0; i < 4; ++i)
        kreg[i] = *(const s16x8*)(Kb + (size_t)(kv0 + 64 + krow + i * 16) * HD + kpos);
    }

    f32x4 sf[4][2];
    if (active) {
      __builtin_amdgcn_s_setprio(1);
#pragma unroll
      for (int mk = 0; mk < 4; ++mk) {
        s16x8 ak[4];
#pragma unroll
        for (int dc = 0; dc < 4; ++dc)
          ak[dc] = *(const s16x8*)(&kt_[cur][mk * 16 + fr][dc * 32 + kg]);
        sf[mk][0] = f32x4{0.f, 0.f, 0.f, 0.f};
        sf[mk][1] = f32x4{0.f, 0.f, 0.f, 0.f};
#pragma unroll
        for (int nq = 0; nq < 2; ++nq)
#pragma unroll
          for (int dc = 0; dc < 4; ++dc)
            sf[mk][nq] = MFMA16(ak[dc], aq[nq][dc], sf[mk][nq]);
      }
      __builtin_amdgcn_s_setprio(0);

#pragma unroll
      for (int mk = 0; mk < 4; ++mk) {
        float4 mv = *(const float4*)(mb + kv0 + mk * 16 + rg);
        float mvr[4] = {mv.x, mv.y, mv.z, mv.w};
#pragma unroll
        for (int nq = 0; nq < 2; ++nq)
#pragma unroll
          for (int r = 0; r < 4; ++r) {
            int kv = kv0 + mk * 16 + rg + r;
            int q  = qw + nq * 16 + fr;
            float v = sf[mk][nq][r] * sc + mvr[r];
            sf[mk][nq][r] = (kv <= q) ? v : -3e38f;
          }
      }

#pragma unroll
      for (int nq = 0; nq < 2; ++nq) {
        float pm = -3e38f;
#pragma unroll
        for (int mk = 0; mk < 4; ++mk)
#pragma unroll
          for (int r = 0; r < 4; ++r) pm = fmaxf(pm, sf[mk][nq][r]);
        pm = fmaxf(pm, __shfl_xor(pm, 16, 64));
        pm = fmaxf(pm, __shfl_xor(pm, 32, 64));
        if (!__all(pm - m_r[nq] <= 8.0f)) {
          float mo = m_r[nq];
          float mn = fmaxf(mo, pm);
          float al = __expf(mo - mn);
          m_r[nq] = mn;
          l_r[nq] *= al;
#pragma unroll
          for (int r = 0; r < 4; ++r) {
            float ar = __shfl(al, rg + r, 16);
#pragma unroll
            for (int od = 0; od < 8; ++od) oacc[nq][od][r] *= ar;
          }
        }
        float rs = 0.f;
#pragma unroll
        for (int mk = 0; mk < 4; ++mk)
#pragma unroll
          for (int r = 0; r < 4; ++r) {
            float p = __expf(sf[mk][nq][r] - m_r[nq]);
            sf[mk][nq][r] = p;
            rs += p;
          }
        rs += __shfl_xor(rs, 16, 64);
        rs += __shfl_xor(rs, 32, 64);
        l_r[nq] += rs;
      }
    }

    if (t + 1 < ntiles) {
#pragma unroll
      for (int i = 0; i < 4; ++i)
        *(s16x8*)(&kt_[cur ^ 1][krow + i * 16][kpos]) = kreg[i];
    }
    __syncthreads();  // B1: vt_=V(t), kt_[cur^1]=K(t+1) visible

    // ---- phase B: issue V(t+1); PV ----
    if (t + 1 < ntiles) {
#pragma unroll
      for (int i = 0; i < 4; ++i) {
        int c = tid + 256 * i;
        vreg[i] = *(const s16x8*)(Vb + (size_t)(c >> 3) * SEQ + kv0 + 64 + (c & 7) * 8);
      }
    }
    if (active) {
#pragma unroll
      for (int kk = 0; kk < 2; ++kk) {
#pragma unroll
        for (int nq = 0; nq < 2; ++nq)
#pragma unroll
          for (int mh = 0; mh < 2; ++mh) {
            int mk = kk * 2 + mh;
            s16x4 pk;
#pragma unroll
            for (int r = 0; r < 4; ++r) pk[r] = (short)f2bf(sf[mk][nq][r]);
            *(s16x4*)(&pt_[w][nq * 16 + fr][mh * 16 + rg]) = pk;
          }
        s16x8 ap[2];
#pragma unroll
        for (int nq = 0; nq < 2; ++nq)
          ap[nq] = *(const s16x8*)(&pt_[w][nq * 16 + fr][kg]);
        __builtin_amdgcn_s_setprio(1);
#pragma unroll
        for (int od = 0; od < 8; ++od) {
          s16x8 bv = *(const s16x8*)(&vt_[od * 16 + fr][kk * 32 + kg]);
#pragma unroll
          for (int nq = 0; nq < 2; ++nq)
            oacc[nq][od] = MFMA16(ap[nq], bv, oacc[nq][od]);
        }
        __builtin_amdgcn_s_setprio(0);
      }
    }
    __syncthreads();  // B2: vt_/kt_[cur] free for overwrite
    cur ^= 1;
  }

  int bS = b * SEQ;
#pragma unroll
  for (int nq = 0; nq < 2; ++nq) {
    float iv = 1.0f / l_r[nq];
    float ivr[4];
#pragma unroll
    for (int r = 0; r < 4; ++r) ivr[r] = __shfl(iv, rg + r, 16);
#pragma unroll
    for (int r = 0; r < 4; ++r) {
      unsigned short* op = O + (size_t)(bS + qw + nq * 16 + rg + r) * 2048 + h * 128 + fr;
#pragma unroll
      for (int od = 0; od < 8; ++od)
        op[od * 16] = f2bf(oacc[nq][od][r] * ivr[r]);
    }
  }
}

extern "C" void kernel_launch(void* const* d_in, const int* in_sizes, int n_in,
                              void* d_out, int out_size, void* d_ws, size_t ws_size,
                              hipStream_t stream) {
  const float* hidden = (const float*)d_in[0];
  const float* mask   = (const float*)d_in[1];
  const float* Wq     = (const float*)d_in[2];
  const float* Wk     = (const float*)d_in[3];
  const float* Wv     = (const float*)d_in[4];
  const float* Wo     = (const float*)d_in[5];
  float* out = (float*)d_out;

  char* ws = (char*)d_ws;
  unsigned short* BT  = (unsigned short*)(ws);                 // 3072x2048 bf16
  unsigned short* WoT = (unsigned short*)(ws + 12582912);      // 2048x2048 bf16
  unsigned short* Qb  = (unsigned short*)(ws + 20971520);      // [B][NH][S][HD]
  unsigned short* Kb  = (unsigned short*)(ws + 37748736);      // [B][NKV][S][HD]
  unsigned short* VT  = (unsigned short*)(ws + 41943040);      // [B][NKV][HD][S]
  unsigned short* AO  = (unsigned short*)(ws + 46137344);      // [MROWS][2048] bf16
  float*          tbl = (float*)(ws + 62914560);               // [S][64][2] f32
  unsigned short* Ab  = AO;  // hidden as bf16; dead before attn writes AO

  conv_bf16<<<MROWS * KDIM / (256 * 8), 256, 0, stream>>>(hidden, Ab);
  transpose_convert<<<dim3(64, 64), 256, 0, stream>>>(Wq, BT, KDIM, 2048);
  transpose_convert<<<dim3(16, 64), 256, 0, stream>>>(Wk, BT + (size_t)2048 * KDIM, KDIM, 512);
  transpose_convert<<<dim3(16, 64), 256, 0, stream>>>(Wv, BT + (size_t)2560 * KDIM, KDIM, 512);
  transpose_convert<<<dim3(64, 64), 256, 0, stream>>>(Wo, WoT, KDIM, 2048);
  rope_table_kernel<<<512, 256, 0, stream>>>(tbl);

  gemm_qkv<<<dim3(NQKV / 128, MROWS / 128), 256, 0, stream>>>(Ab, BT, Qb, Kb, VT);
  rope2<<<(BATCH * NH * SEQ) / 32, 256, 0, stream>>>(Qb, tbl);
  rope2<<<(BATCH * NKV * SEQ) / 32, 256, 0, stream>>>(Kb, tbl);
  attn_fwd<<<dim3(512), 256, 0, stream>>>(Qb, Kb, VT, mask, AO);
  gemm_out<<<dim3(2048 / 128, MROWS / 128), 256, 0, stream>>>(AO, WoT, out);
}